// Round 18
// baseline (425.612 us; speedup 1.0000x reference)
//
#include <hip/hip_runtime.h>
#include <hip/hip_bf16.h>

// Problem constants
#define NB 8
#define NL 2500
#define ND 512
#define NY 8921

// Tiling
#define BM 256             // G rows per block (128 labels, U/W interleaved)
#define BN 256             // l-tile
#define BK 32              // k-slice
#define NKS 16             // ND/BK slices per l-tile
#define LPAD 2560          // 10 * 256
#define NLT 10             // LPAD/BN
#define NYB 70             // ceil(NY/128)
#define YPAD 8960          // NYB*128

#define SPLIT 5            // l-range splits (2 l-tiles per block)
#define LSPL_MAIN 2

#define TILE 16384         // A: 256 rows x 32 bf16, row-pair swizzled image
#define XSTEP 16384        // B: one (t,ks) granule-major tile: [g 4][r 256]*16B
#define GT_BYTES ((size_t)NYB * NKS * TILE)              // 18,350,080
#define XT_BYTES ((size_t)NB * NLT * NKS * XSTEP)        // 20,971,520
#define P_ELEMS  ((size_t)SPLIT * NB * YPAD)             // 358,400
#define P_BYTES  (P_ELEMS * 4)

typedef short s8v __attribute__((ext_vector_type(8)));
typedef float f4v __attribute__((ext_vector_type(4)));

__device__ __forceinline__ unsigned short f2bf(float f) {
  unsigned int u = __float_as_uint(f);
  return (unsigned short)((u + 0x7FFFu + ((u >> 16) & 1u)) >> 16);
}
__device__ __forceinline__ unsigned int pk2(float a, float b) {
  return (unsigned int)f2bf(a) | ((unsigned int)f2bf(b) << 16);
}
__device__ __forceinline__ void async_copy16(const char* g, char* l) {
  __builtin_amdgcn_global_load_lds(
      (const __attribute__((address_space(1))) void*)g,
      (__attribute__((address_space(3))) void*)l, 16, 0, 0);
}

// Swizzled A-tile byte offset (proven conflict-free for the 16x16 read pattern)
__device__ __forceinline__ int tile_off(int r, int gn) {
  int rp = r >> 1;
  return rp * 128 + ((((r & 1) << 6) | (gn << 4)) ^ ((rp & 7) << 4));
}

// ---- G: interleave U/W rows (row 2y=U[y], 2y+1=W[y]) -> bf16 swizzled slice-tiles
__global__ void cvt_g_kernel(const float* __restrict__ U, const float* __restrict__ W,
                             char* __restrict__ Gt) {
  int c = blockIdx.x * 256 + threadIdx.x;      // one 16B granule
  int g10 = c & 1023;
  int tile = c >> 10;                          // yblk*16 + ks
  int ks = tile & 15, yblk = tile >> 4;
  int r = g10 >> 2, gn = g10 & 3;
  int rg = yblk * 256 + r;
  int y = rg >> 1;
  uint4 o;
  if (y < NY) {
    const float* src = (rg & 1) ? W : U;
    const float4* p = (const float4*)(src + (size_t)y * ND + ks * BK + gn * 8);
    float4 f0 = p[0], f1 = p[1];
    o.x = pk2(f0.x, f0.y); o.y = pk2(f0.z, f0.w);
    o.z = pk2(f1.x, f1.y); o.w = pk2(f1.z, f1.w);
  } else {
    o = make_uint4(0u, 0u, 0u, 0u);
  }
  *(uint4*)(Gt + (size_t)tile * TILE + tile_off(r, gn)) = o;
}

// ---- x -> bf16 granule-major tiles for DIRECT L2 reads:
// Xt[b][t][ks][g][r]: granule (16B = 8 k-elems) at c = (((b*10+t)*16+ks)*4+g)*256 + r.
// A wave's bv[ni] load = 16 lanes x 16B contiguous (256B) per g-group: full 64B lines.
__global__ void cvt_x_kernel(const float* __restrict__ x, char* __restrict__ Xt) {
  int c = blockIdx.x * 256 + threadIdx.x;
  int r  = c & 255;
  int g  = (c >> 8) & 3;
  int ks = (c >> 10) & 15;
  int bt = c >> 14;
  int t = bt % NLT, b = bt / NLT;
  int l = t * 256 + r;
  uint4 o;
  if (l < NL) {
    const float4* p = (const float4*)(x + ((size_t)b * NL + l) * ND + ks * BK + g * 8);
    float4 f0 = p[0], f1 = p[1];
    o.x = pk2(f0.x, f0.y); o.y = pk2(f0.z, f0.w);
    o.z = pk2(f1.x, f1.y); o.w = pk2(f1.z, f1.w);
  } else {
    o = make_uint4(0u, 0u, 0u, 0u);
  }
  *(uint4*)(Xt + (size_t)c * 16) = o;          // linear coalesced store
}

// ---- fused dual-GEMM + deferred softmax; 512 thr = 8 waves (2M x 4N), 256x256 tile
// B (x) read DIRECTLY from L2-resident global into registers (VMEM pipe);
// only A staged in LDS (ring-2, 32KB) -> DS-pipe reads cut 33%, B-staging gone.
// ROUND-16 BUG FIX: step boundary uses COUNTED VMC(4), not VMC(0) — issue order
// pinned [stageA x2, bv x4] by sched_barriers, so VMC(4) retires exactly the A
// staging (slot must land for next step) while B loads stay in flight until
// their MFMA use next step (compiler inserts the counted wait).
template<int LSPL, int NSPL, bool PARTIAL>
__global__ __launch_bounds__(512, 2) void fused_kernel(
    const char* __restrict__ Gt, const char* __restrict__ Xt,
    const float* __restrict__ bias, float* __restrict__ out,
    float* __restrict__ PD, float* __restrict__ PN)
{
  __shared__ uint4 ring[2048];         // 32 KB: two 16KB A slots
  char* ringC = (char*)ring;

  constexpr int NS = LSPL * NKS;       // K-steps per block

  const int tid  = threadIdx.x;
  const int lane = tid & 63;
  const int w    = tid >> 6;           // 0..7
  const int wr   = w >> 2;             // 0..1  M-half (128 G-rows)
  const int wc   = w & 3;              // 0..3  N-quarter (64 l)
  const int cl   = lane & 15, g4 = lane >> 4;

  const int id    = blockIdx.x;
  const int bb    = id & 7;            // batch, XCD-pinned
  const int n     = id >> 3;
  const int yblk  = n / NSPL;
  const int split = n - yblk * NSPL;
  const int tbase = split * LSPL;

  const char* GA = Gt + (size_t)yblk * NKS * TILE;
  const char* XB = Xt + (size_t)(bb * NLT + tbase) * NKS * XSTEP;

  f4v acc[8][4];
  float runD[8][2], runN[8][2];
  #pragma unroll
  for (int mi = 0; mi < 8; ++mi)
    #pragma unroll
    for (int p = 0; p < 2; ++p) { runD[mi][p] = 0.f; runN[mi][p] = 0.f; }

  // A-fragment LDS offsets (within a slot)
  int aoff[8];
  #pragma unroll
  for (int j = 0; j < 8; ++j) aoff[j] = tile_off(wr * 128 + j * 16 + cl, g4);
  // B global offset base within a (t,ks) tile
  const int boffg = g4 * 4096 + (wc * 64 + cl) * 16;

  const int t16 = tid << 4;
  auto stageA = [&](int s) {           // 2 vm-events/wave: A slice s -> slot s&1
    const char* ga = GA + (size_t)(s & 15) * TILE;
    char* la = ringC + (s & 1) * TILE + (w << 10);
    async_copy16(ga + t16, la);
    async_copy16(ga + 8192 + t16, la + 8192);
  };

  auto softmax_acc = [&](int tt) {     // deferred: per-lane sums (no shuffles)
    const int lbase = (tbase + tt) * BN + wc * 64 + cl;
    #pragma unroll
    for (int mi = 0; mi < 8; ++mi) {
      #pragma unroll
      for (int p = 0; p < 2; ++p) {
        float se = 0.f, ste = 0.f;
        #pragma unroll
        for (int ni = 0; ni < 4; ++ni) {
          bool valid = (lbase + ni * 16) < NL;
          float sv = valid ? acc[mi][ni][2 * p] : -1e30f;   // exp(-1e30) == 0
          float e = __expf(sv);
          se += e;
          ste += e * acc[mi][ni][2 * p + 1];
        }
        runD[mi][p] += se;
        runN[mi][p] += ste;
      }
    }
  };

#define SBAR __builtin_amdgcn_sched_barrier(0)
#define VMC(N)  asm volatile("s_waitcnt vmcnt(" #N ")" ::: "memory")

  // prologue: stage A(0), load bv(0), drain once, publish
  s8v bvA[4], bvB[4];
  stageA(0);
  {
    const char* bsrc = XB + boffg;
    #pragma unroll
    for (int ni = 0; ni < 4; ++ni) bvA[ni] = *(const s8v*)(bsrc + ni * 256);
  }
  VMC(0);
  __builtin_amdgcn_s_barrier();
  asm volatile("" ::: "memory");

#define K_STEP(U, BVC, BVN)                                                    \
  do {                                                                         \
    const int u_  = (U);                                                       \
    const int ks_ = u_ & (NKS - 1);                                            \
    const char* A_ = ringC + (u_ & 1) * TILE;                                  \
    if (ks_ == 0) {                                                            \
      _Pragma("unroll")                                                        \
      for (int mi = 0; mi < 8; ++mi)                                           \
        _Pragma("unroll")                                                      \
        for (int ni = 0; ni < 4; ++ni)                                         \
          _Pragma("unroll")                                                    \
          for (int q = 0; q < 4; ++q) acc[mi][ni][q] = 0.f;                    \
    }                                                                          \
    const bool hn_ = (u_ + 1 < NS);                                            \
    if (hn_) stageA(u_ + 1);          /* 2 vm events, oldest */                \
    SBAR;                                                                      \
    if (hn_) {                                                                 \
      const int un_ = u_ + 1;                                                  \
      const char* bsrc_ = XB + (size_t)(un_ >> 4) * (NKS * XSTEP)              \
                        + (size_t)(un_ & 15) * XSTEP + boffg;                  \
      _Pragma("unroll")                                                        \
      for (int ni = 0; ni < 4; ++ni) BVN[ni] = *(const s8v*)(bsrc_ + ni * 256);\
    }                                                                          \
    SBAR;                              /* pin order: [A,A,bv,bv,bv,bv] */      \
    s8v af03[4], af47[4];                                                      \
    _Pragma("unroll")                                                          \
    for (int j = 0; j < 4; ++j) af03[j] = *(const s8v*)(A_ + aoff[j]);         \
    __builtin_amdgcn_s_setprio(1);                                             \
    _Pragma("unroll")                                                          \
    for (int j = 0; j < 4; ++j)                                                \
      _Pragma("unroll")                                                        \
      for (int ni = 0; ni < 4; ++ni)                                           \
        acc[j][ni] = __builtin_amdgcn_mfma_f32_16x16x32_bf16(                  \
            af03[j], BVC[ni], acc[j][ni], 0, 0, 0);                            \
    __builtin_amdgcn_s_setprio(0);                                             \
    _Pragma("unroll")                                                          \
    for (int j = 0; j < 4; ++j) af47[j] = *(const s8v*)(A_ + aoff[4 + j]);     \
    __builtin_amdgcn_s_setprio(1);                                             \
    _Pragma("unroll")                                                          \
    for (int j = 0; j < 4; ++j)                                                \
      _Pragma("unroll")                                                        \
      for (int ni = 0; ni < 4; ++ni)                                           \
        acc[4 + j][ni] = __builtin_amdgcn_mfma_f32_16x16x32_bf16(              \
            af47[j], BVC[ni], acc[4 + j][ni], 0, 0, 0);                        \
    __builtin_amdgcn_s_setprio(0);                                             \
    if (ks_ == NKS - 1) softmax_acc(u_ >> 4);                                  \
    if (hn_) {                                                                 \
      VMC(4);                          /* retire A staging; bv stays in flight */ \
      SBAR;                                                                    \
      __builtin_amdgcn_s_barrier();                                            \
      asm volatile("" ::: "memory");                                           \
    }                                                                          \
  } while (0)

  for (int uu = 0; uu < NS; uu += 2) {
    K_STEP(uu,     bvA, bvB);
    K_STEP(uu + 1, bvB, bvA);
  }
#undef K_STEP

  VMC(0);

  // ---- once-per-kernel: 16-lane reduce of partials (plain sums)
  #pragma unroll
  for (int mi = 0; mi < 8; ++mi)
    #pragma unroll
    for (int p = 0; p < 2; ++p) {
      float d = runD[mi][p], nn = runN[mi][p];
      #pragma unroll
      for (int off = 1; off < 16; off <<= 1) {
        d += __shfl_xor(d, off);
        nn += __shfl_xor(nn, off);
      }
      runD[mi][p] = d; runN[mi][p] = nn;
    }

  // ---- 4-way wc merge via LDS (plain sums), then write partials / output
  __syncthreads();
  float* sm = (float*)ring;      // 128 labels x 4 wc x 2 floats = 4 KB
  if (cl == 0) {
    #pragma unroll
    for (int mi = 0; mi < 8; ++mi)
      #pragma unroll
      for (int p = 0; p < 2; ++p) {
        int lab = wr * 64 + mi * 8 + 2 * g4 + p;   // 0..127
        float* s2 = sm + (lab * 4 + wc) * 2;
        s2[0] = runD[mi][p]; s2[1] = runN[mi][p];
      }
  }
  __syncthreads();
  if (tid < 128) {
    float D = 0.f, N = 0.f;
    #pragma unroll
    for (int q = 0; q < 4; ++q) {
      const float* s2 = sm + (tid * 4 + q) * 2;
      D += s2[0]; N += s2[1];
    }
    int y = yblk * 128 + tid;
    if constexpr (PARTIAL) {
      size_t o = ((size_t)split * NB + bb) * YPAD + y;
      PD[o] = D; PN[o] = N;
    } else {
      if (y < NY) out[(size_t)bb * NY + y] = N / D + bias[y];
    }
  }
}

// ---- merge SPLIT partials + bias -> out (plain sums)
__global__ void merge_kernel(const float* __restrict__ PD, const float* __restrict__ PN,
                             const float* __restrict__ bias, float* __restrict__ out) {
  int idx = blockIdx.x * 256 + threadIdx.x;      // NB*YPAD
  int b = idx / YPAD, y = idx - b * YPAD;
  if (y >= NY) return;
  float D = 0.f, N = 0.f;
  #pragma unroll
  for (int s = 0; s < SPLIT; ++s) {
    size_t o = ((size_t)s * NB + b) * YPAD + y;
    D += PD[o];
    N += PN[o];
  }
  out[(size_t)b * NY + y] = N / D + bias[y];
}

extern "C" void kernel_launch(void* const* d_in, const int* in_sizes, int n_in,
                              void* d_out, int out_size, void* d_ws, size_t ws_size,
                              hipStream_t stream) {
  const float* xf   = (const float*)d_in[0];
  const float* Uf   = (const float*)d_in[1];
  const float* Wf   = (const float*)d_in[2];
  const float* bias = (const float*)d_in[3];
  float* out = (float*)d_out;

  char* Gt = (char*)d_ws;
  char* Xt = Gt + GT_BYTES;
  float* PD = (float*)(Xt + XT_BYTES);
  float* PN = PD + P_ELEMS;

  // G granules: 1,146,880 / 256 = 4480 blocks ; X granules: 1,310,720 / 256 = 5120
  cvt_g_kernel<<<4480, 256, 0, stream>>>(Uf, Wf, Gt);
  cvt_x_kernel<<<5120, 256, 0, stream>>>(xf, Xt);

  const size_t need_main = GT_BYTES + XT_BYTES + 2 * P_BYTES;   // ~42.2 MB
  if (ws_size >= need_main) {
    fused_kernel<LSPL_MAIN, SPLIT, true><<<NYB * NB * SPLIT, 512, 0, stream>>>(
        Gt, Xt, bias, out, PD, PN);
    merge_kernel<<<NB * YPAD / 256, 256, 0, stream>>>(PD, PN, bias, out);
  } else {
    fused_kernel<NLT, 1, false><<<NYB * NB, 512, 0, stream>>>(
        Gt, Xt, bias, out, PD, PN);
  }
}

// Round 19
// 359.580 us; speedup vs baseline: 1.1836x; 1.1836x over previous
//
#include <hip/hip_runtime.h>
#include <hip/hip_bf16.h>

// Problem constants
#define NB 8
#define NL 2500
#define ND 512
#define NY 8921

// Tiling
#define BM 256             // G rows per block (128 labels, U/W interleaved)
#define BN 256             // l-tile
#define BK 32              // k-slice (2 slices per K-tile of 64)
#define NKS 16             // slices per l-tile
#define LPAD 2560          // 10 * 256
#define NLT 10             // LPAD/BN
#define NYB 70             // ceil(NY/128)
#define YPAD 8960          // NYB*128

#define SPLIT 5            // l-range splits (2 l-tiles per block)
#define LSPL_MAIN 2

#define TILE 16384         // 256 rows x 32 bf16 (64B/row), row-pair swizzled image
#define GT_BYTES ((size_t)NYB * NKS * TILE)              // 18,350,080
#define XT_BYTES ((size_t)NB * NLT * NKS * TILE)         // 20,971,520
#define P_ELEMS  ((size_t)SPLIT * NB * YPAD)             // 358,400
#define P_BYTES  (P_ELEMS * 4)

#define GCVT_BLKS 4480     // G granules: 17920 rows * 64 / 256
#define XCVT_BLKS 5120     // X granules: 20480 rows * 64 / 256

typedef short s8v __attribute__((ext_vector_type(8)));
typedef float f4v __attribute__((ext_vector_type(4)));

__device__ __forceinline__ unsigned short f2bf(float f) {
  unsigned int u = __float_as_uint(f);
  return (unsigned short)((u + 0x7FFFu + ((u >> 16) & 1u)) >> 16);
}
__device__ __forceinline__ unsigned int pk2(float a, float b) {
  return (unsigned int)f2bf(a) | ((unsigned int)f2bf(b) << 16);
}
__device__ __forceinline__ void async_copy16(const char* g, char* l) {
  __builtin_amdgcn_global_load_lds(
      (const __attribute__((address_space(1))) void*)g,
      (__attribute__((address_space(3))) void*)l, 16, 0, 0);
}

// Swizzled tile byte offset for (row r in [0,256), 16B-granule gn in [0,4)):
// row-pair rp=r>>1 owns a 128B line; within-line = ((r&1)*64 + gn*16) ^ ((rp&7)<<4)
__device__ __forceinline__ int tile_off(int r, int gn) {
  int rp = r >> 1;
  return rp * 128 + ((((r & 1) << 6) | (gn << 4)) ^ ((rp & 7) << 4));
}

// ---- merged conversion: one launch does both G and X images (co-fills GPU)
// blocks [0, 4480): G interleave U/W rows (row 2y=U[y], 2y+1=W[y]) -> swizzled tiles
// blocks [4480, 9600): x -> bf16 swizzled tiles [b 8][t 10][ks 16][16KB], zero-pad
__global__ void cvt_all_kernel(const float* __restrict__ U, const float* __restrict__ W,
                               const float* __restrict__ x,
                               char* __restrict__ Gt, char* __restrict__ Xt) {
  if (blockIdx.x < GCVT_BLKS) {
    int c = blockIdx.x * 256 + threadIdx.x;    // one 16B granule
    int g10 = c & 1023;
    int tile = c >> 10;                        // yblk*16 + ks
    int ks = tile & 15, yblk = tile >> 4;
    int r = g10 >> 2, gn = g10 & 3;
    int rg = yblk * 256 + r;
    int y = rg >> 1;
    uint4 o;
    if (y < NY) {
      const float* src = (rg & 1) ? W : U;
      const float4* p = (const float4*)(src + (size_t)y * ND + ks * BK + gn * 8);
      float4 f0 = p[0], f1 = p[1];
      o.x = pk2(f0.x, f0.y); o.y = pk2(f0.z, f0.w);
      o.z = pk2(f1.x, f1.y); o.w = pk2(f1.z, f1.w);
    } else {
      o = make_uint4(0u, 0u, 0u, 0u);
    }
    *(uint4*)(Gt + (size_t)tile * TILE + tile_off(r, gn)) = o;
  } else {
    int c = (blockIdx.x - GCVT_BLKS) * 256 + threadIdx.x;
    int g10 = c & 1023;
    int tile = c >> 10;                        // (b*10+t)*16 + ks
    int ks = tile & 15, rest = tile >> 4;
    int t = rest % NLT, b = rest / NLT;
    int r = g10 >> 2, gn = g10 & 3;
    int l = t * 256 + r;
    uint4 o;
    if (l < NL) {
      const float4* p = (const float4*)(x + ((size_t)b * NL + l) * ND + ks * BK + gn * 8);
      float4 f0 = p[0], f1 = p[1];
      o.x = pk2(f0.x, f0.y); o.y = pk2(f0.z, f0.w);
      o.z = pk2(f1.x, f1.y); o.w = pk2(f1.z, f1.w);
    } else {
      o = make_uint4(0u, 0u, 0u, 0u);
    }
    *(uint4*)(Xt + (size_t)tile * TILE + tile_off(r, gn)) = o;
  }
}

// ---- fused dual-GEMM + deferred softmax; 512 thr = 8 waves (2M x 4N), 256x256 tile
// m201-complete schedule: K-tile = 64 (2 slices), 2 LDS buffers (A 2x32K, B 2x32K),
// 4 quadrant phases per K-tile, each {stage half-tile || read next-quadrant frags ->
// barrier -> counted lgkm -> setprio + 16 MFMA -> (vmcnt(2) at ph0/ph2) -> barrier}.
// vmcnt waits precede a barrier (stage chunks are cross-wave; publish needs both).
// Min 2 vm-events in flight mid-loop (never drains). Register read-ahead: frags for
// quadrant Q are read one phase earlier; counted lgkm(4/8) retires them exactly.
template<int LSPL, int NSPL, bool PARTIAL>
__global__ __launch_bounds__(512, 2) void fused_kernel(
    const char* __restrict__ Gt, const char* __restrict__ Xt,
    const float* __restrict__ bias, float* __restrict__ out,
    float* __restrict__ PD, float* __restrict__ PN)
{
  __shared__ uint4 ring[8192];         // 128 KB: A bufs [0,64K), B bufs [64K,128K)
  char* ringC = (char*)ring;

  constexpr int NKT = LSPL * 8;        // K-tiles (BK=64) per block

  const int tid  = threadIdx.x;
  const int lane = tid & 63;
  const int w    = tid >> 6;           // 0..7
  const int wr   = w >> 2;             // 0..1  M-half (128 G-rows)
  const int wc   = w & 3;              // 0..3  N-quarter (64 l)
  const int cl   = lane & 15, g = lane >> 4;

  const int id    = blockIdx.x;
  const int bb    = id & 7;            // batch, XCD-pinned
  const int n     = id >> 3;
  const int yblk  = n / NSPL;
  const int split = n - yblk * NSPL;
  const int tbase = split * LSPL;

  const char* GA = Gt + (size_t)yblk * NKS * TILE;
  const char* XB = Xt + ((size_t)bb * NLT + tbase) * NKS * TILE;

  f4v acc[8][4];
  float runD[8][2], runN[8][2];
  #pragma unroll
  for (int mi = 0; mi < 8; ++mi)
    #pragma unroll
    for (int p = 0; p < 2; ++p) { runD[mi][p] = 0.f; runN[mi][p] = 0.f; }

  int aoff[8], boff[4];
  #pragma unroll
  for (int j = 0; j < 8; ++j) aoff[j] = tile_off(wr * 128 + j * 16 + cl, g);
  #pragma unroll
  for (int ni = 0; ni < 4; ++ni) boff[ni] = tile_off(wc * 64 + ni * 16 + cl, g);

  const int t16 = tid << 4;
  auto stgA = [&](int kt1, int par) {  // 2 vm-events/wave: A slice -> buf kt1&1
    const char* ga = GA + (size_t)((((kt1 & 7) << 1) | par)) * TILE;
    char* la = ringC + (kt1 & 1) * 32768 + par * 16384 + (w << 10);
    async_copy16(ga + t16, la);
    async_copy16(ga + 8192 + t16, la + 8192);
  };
  auto stgB = [&](int kt1, int par) {
    const char* gb = XB + (size_t)((kt1 >> 3) * 16 + ((kt1 & 7) << 1) + par) * TILE;
    char* lb = ringC + 65536 + (kt1 & 1) * 32768 + par * 16384 + (w << 10);
    async_copy16(gb + t16, lb);
    async_copy16(gb + 8192 + t16, lb + 8192);
  };

  auto softmax_acc = [&](int tt) {     // deferred: per-lane sums, no shuffles
    const int lbase = (tbase + tt) * BN + wc * 64 + cl;
    #pragma unroll
    for (int mi = 0; mi < 8; ++mi) {
      #pragma unroll
      for (int p = 0; p < 2; ++p) {
        float se = 0.f, ste = 0.f;
        #pragma unroll
        for (int ni = 0; ni < 4; ++ni) {
          bool valid = (lbase + ni * 16) < NL;
          float sv = valid ? acc[mi][ni][2 * p] : -1e30f;
          float e = __expf(sv);
          se += e;
          ste += e * acc[mi][ni][2 * p + 1];
        }
        runD[mi][p] += se;
        runN[mi][p] += ste;
      }
    }
  };

#define SBAR __builtin_amdgcn_sched_barrier(0)
#define LGKM(N) asm volatile("s_waitcnt lgkmcnt(" #N ")" ::: "memory")
#define VMC(N)  asm volatile("s_waitcnt vmcnt(" #N ")" ::: "memory")

  // prologue: stage K-tile 0 fully (8 events); retire even half (vmcnt 4); publish
  stgA(0, 0); stgB(0, 0); stgA(0, 1); stgB(0, 1);
  VMC(4);
  __builtin_amdgcn_s_barrier();
  asm volatile("" ::: "memory");

  // frag registers (named sets, static indexing)
  s8v bvE[4], bvO[4], afX[4], afY[4];
  // primer: Q0 reads of kt=0 (even slice, buf 0)
  #pragma unroll
  for (int ni = 0; ni < 4; ++ni) bvE[ni] = *(const s8v*)(ringC + 65536 + boff[ni]);
  #pragma unroll
  for (int j = 0; j < 4; ++j)    afX[j] = *(const s8v*)(ringC + aoff[j]);

  for (int kt = 0; kt < NKT; ++kt) {
    const int buf = kt & 1;
    const char* Ae = ringC + buf * 32768;
    const char* Ao = Ae + 16384;
    const char* Bo = ringC + 65536 + buf * 32768 + 16384;
    const char* Aen = ringC + (buf ^ 1) * 32768;
    const char* Ben = ringC + 65536 + (buf ^ 1) * 32768;
    const bool hn = (kt + 1) < NKT;

    if ((kt & 7) == 0) {
      if (kt > 0) softmax_acc((kt >> 3) - 1);
      #pragma unroll
      for (int mi = 0; mi < 8; ++mi)
        #pragma unroll
        for (int ni = 0; ni < 4; ++ni)
          #pragma unroll
          for (int q = 0; q < 4; ++q) acc[mi][ni][q] = 0.f;
    }

    // ---- ph0: stage As0' | read afY(even hi) -> MFMA Q0 (afX,bvE) -> W1 -> bar
    if (hn) stgA(kt + 1, 0);
    #pragma unroll
    for (int j = 0; j < 4; ++j) afY[j] = *(const s8v*)(Ae + aoff[4 + j]);
    SBAR;
    __builtin_amdgcn_s_barrier();
    LGKM(4); SBAR;
    __builtin_amdgcn_s_setprio(1);
    #pragma unroll
    for (int j = 0; j < 4; ++j)
      #pragma unroll
      for (int ni = 0; ni < 4; ++ni)
        acc[j][ni] = __builtin_amdgcn_mfma_f32_16x16x32_bf16(afX[j], bvE[ni], acc[j][ni], 0, 0, 0);
    __builtin_amdgcn_s_setprio(0);
    if (hn) { VMC(2); } else { VMC(0); }   // publish odd half of THIS K-tile
    SBAR;
    __builtin_amdgcn_s_barrier();
    asm volatile("" ::: "memory");

    // ---- ph1: stage Bs0' | read bvO+afX(odd lo) -> MFMA Q1 (afY,bvE) -> bar
    if (hn) stgB(kt + 1, 0);
    #pragma unroll
    for (int ni = 0; ni < 4; ++ni) bvO[ni] = *(const s8v*)(Bo + boff[ni]);
    #pragma unroll
    for (int j = 0; j < 4; ++j)    afX[j] = *(const s8v*)(Ao + aoff[j]);
    SBAR;
    __builtin_amdgcn_s_barrier();
    LGKM(8); SBAR;
    __builtin_amdgcn_s_setprio(1);
    #pragma unroll
    for (int j = 0; j < 4; ++j)
      #pragma unroll
      for (int ni = 0; ni < 4; ++ni)
        acc[4 + j][ni] = __builtin_amdgcn_mfma_f32_16x16x32_bf16(afY[j], bvE[ni], acc[4 + j][ni], 0, 0, 0);
    __builtin_amdgcn_s_setprio(0);
    SBAR;
    __builtin_amdgcn_s_barrier();
    asm volatile("" ::: "memory");

    // ---- ph2: stage As1' | read afY(odd hi) -> MFMA Q2 (afX,bvO) -> W2 -> bar
    if (hn) stgA(kt + 1, 1);
    #pragma unroll
    for (int j = 0; j < 4; ++j) afY[j] = *(const s8v*)(Ao + aoff[4 + j]);
    SBAR;
    __builtin_amdgcn_s_barrier();
    LGKM(4); SBAR;
    __builtin_amdgcn_s_setprio(1);
    #pragma unroll
    for (int j = 0; j < 4; ++j)
      #pragma unroll
      for (int ni = 0; ni < 4; ++ni)
        acc[j][ni] = __builtin_amdgcn_mfma_f32_16x16x32_bf16(afX[j], bvO[ni], acc[j][ni], 0, 0, 0);
    __builtin_amdgcn_s_setprio(0);
    if (hn) VMC(2);                        // publish even half of NEXT K-tile
    SBAR;
    __builtin_amdgcn_s_barrier();
    asm volatile("" ::: "memory");

    // ---- ph3: stage Bs1' | read bvE'+afX'(next even lo) -> MFMA Q3 (afY,bvO) -> bar
    if (hn) {
      stgB(kt + 1, 1);
      #pragma unroll
      for (int ni = 0; ni < 4; ++ni) bvE[ni] = *(const s8v*)(Ben + boff[ni]);
      #pragma unroll
      for (int j = 0; j < 4; ++j)    afX[j] = *(const s8v*)(Aen + aoff[j]);
      SBAR;
      __builtin_amdgcn_s_barrier();
      LGKM(8); SBAR;
    } else {
      SBAR;
      __builtin_amdgcn_s_barrier();
      LGKM(0); SBAR;
    }
    __builtin_amdgcn_s_setprio(1);
    #pragma unroll
    for (int j = 0; j < 4; ++j)
      #pragma unroll
      for (int ni = 0; ni < 4; ++ni)
        acc[4 + j][ni] = __builtin_amdgcn_mfma_f32_16x16x32_bf16(afY[j], bvO[ni], acc[4 + j][ni], 0, 0, 0);
    __builtin_amdgcn_s_setprio(0);
    SBAR;
    __builtin_amdgcn_s_barrier();
    asm volatile("" ::: "memory");
  }
  softmax_acc(LSPL - 1);

#undef SBAR
#undef LGKM
#undef VMC

  // ---- once-per-kernel: 16-lane reduce of partials (plain sums)
  #pragma unroll
  for (int mi = 0; mi < 8; ++mi)
    #pragma unroll
    for (int p = 0; p < 2; ++p) {
      float d = runD[mi][p], nn = runN[mi][p];
      #pragma unroll
      for (int off = 1; off < 16; off <<= 1) {
        d += __shfl_xor(d, off);
        nn += __shfl_xor(nn, off);
      }
      runD[mi][p] = d; runN[mi][p] = nn;
    }

  // ---- 4-way wc merge via LDS (plain sums), then write partials / output
  __syncthreads();
  float* sm = (float*)ring;      // 128 labels x 4 wc x 2 floats = 4 KB
  if (cl == 0) {
    #pragma unroll
    for (int mi = 0; mi < 8; ++mi)
      #pragma unroll
      for (int p = 0; p < 2; ++p) {
        int lab = wr * 64 + mi * 8 + 2 * g + p;   // 0..127
        float* s2 = sm + (lab * 4 + wc) * 2;
        s2[0] = runD[mi][p]; s2[1] = runN[mi][p];
      }
  }
  __syncthreads();
  if (tid < 128) {
    float D = 0.f, N = 0.f;
    #pragma unroll
    for (int q = 0; q < 4; ++q) {
      const float* s2 = sm + (tid * 4 + q) * 2;
      D += s2[0]; N += s2[1];
    }
    int y = yblk * 128 + tid;
    if constexpr (PARTIAL) {
      size_t o = ((size_t)split * NB + bb) * YPAD + y;
      PD[o] = D; PN[o] = N;
    } else {
      if (y < NY) out[(size_t)bb * NY + y] = N / D + bias[y];
    }
  }
}

// ---- merge SPLIT partials + bias -> out (plain sums)
__global__ void merge_kernel(const float* __restrict__ PD, const float* __restrict__ PN,
                             const float* __restrict__ bias, float* __restrict__ out) {
  int idx = blockIdx.x * 256 + threadIdx.x;      // NB*YPAD
  int b = idx / YPAD, y = idx - b * YPAD;
  if (y >= NY) return;
  float D = 0.f, N = 0.f;
  #pragma unroll
  for (int s = 0; s < SPLIT; ++s) {
    size_t o = ((size_t)s * NB + b) * YPAD + y;
    D += PD[o];
    N += PN[o];
  }
  out[(size_t)b * NY + y] = N / D + bias[y];
}

extern "C" void kernel_launch(void* const* d_in, const int* in_sizes, int n_in,
                              void* d_out, int out_size, void* d_ws, size_t ws_size,
                              hipStream_t stream) {
  const float* xf   = (const float*)d_in[0];
  const float* Uf   = (const float*)d_in[1];
  const float* Wf   = (const float*)d_in[2];
  const float* bias = (const float*)d_in[3];
  float* out = (float*)d_out;

  char* Gt = (char*)d_ws;
  char* Xt = Gt + GT_BYTES;
  float* PD = (float*)(Xt + XT_BYTES);
  float* PN = PD + P_ELEMS;

  // merged conversion: G blocks [0,4480) + X blocks [4480,9600), one launch
  cvt_all_kernel<<<GCVT_BLKS + XCVT_BLKS, 256, 0, stream>>>(Uf, Wf, xf, Gt, Xt);

  const size_t need_main = GT_BYTES + XT_BYTES + 2 * P_BYTES;   // ~42.2 MB
  if (ws_size >= need_main) {
    fused_kernel<LSPL_MAIN, SPLIT, true><<<NYB * NB * SPLIT, 512, 0, stream>>>(
        Gt, Xt, bias, out, PD, PN);
    merge_kernel<<<NB * YPAD / 256, 256, 0, stream>>>(PD, PN, bias, out);
  } else {
    fused_kernel<NLT, 1, false><<<NYB * NB, 512, 0, stream>>>(
        Gt, Xt, bias, out, PD, PN);
  }
}

// Round 20
// 354.540 us; speedup vs baseline: 1.2005x; 1.0142x over previous
//
#include <hip/hip_runtime.h>
#include <hip/hip_bf16.h>

// Problem constants
#define NB 8
#define NL 2500
#define ND 512
#define NY 8921

// Tiling
#define BM 256             // G rows per block (128 labels, U/W interleaved)
#define BN 256             // l-tile
#define BK 32              // k-slice (2 slices per K-tile of 64)
#define NKS 16             // slices per l-tile
#define LPAD 2560          // 10 * 256
#define NLT 10             // LPAD/BN
#define NYB 70             // ceil(NY/128)
#define YPAD 8960          // NYB*128

#define SPLIT 5            // l-range splits (2 l-tiles per block)
#define LSPL_MAIN 2

#define TILE 16384         // 256 rows x 32 bf16 (64B/row), row-pair swizzled image
#define GT_BYTES ((size_t)NYB * NKS * TILE)              // 18,350,080
#define XT_BYTES ((size_t)NB * NLT * NKS * TILE)         // 20,971,520
#define P_ELEMS  ((size_t)SPLIT * NB * YPAD)             // 358,400
#define P_BYTES  (P_ELEMS * 4)

#define GCVT_BLKS 4480     // G granules: 17920 rows * 64 / 256
#define XCVT_BLKS 5120     // X granules: 20480 rows * 64 / 256

typedef short s8v __attribute__((ext_vector_type(8)));
typedef float f4v __attribute__((ext_vector_type(4)));

__device__ __forceinline__ unsigned short f2bf(float f) {
  unsigned int u = __float_as_uint(f);
  return (unsigned short)((u + 0x7FFFu + ((u >> 16) & 1u)) >> 16);
}
__device__ __forceinline__ unsigned int pk2(float a, float b) {
  return (unsigned int)f2bf(a) | ((unsigned int)f2bf(b) << 16);
}
__device__ __forceinline__ void async_copy16(const char* g, char* l) {
  __builtin_amdgcn_global_load_lds(
      (const __attribute__((address_space(1))) void*)g,
      (__attribute__((address_space(3))) void*)l, 16, 0, 0);
}

// Swizzled tile byte offset for (row r in [0,256), 16B-granule gn in [0,4)):
// row-pair rp=r>>1 owns a 128B line; within-line = ((r&1)*64 + gn*16) ^ ((rp&7)<<4)
__device__ __forceinline__ int tile_off(int r, int gn) {
  int rp = r >> 1;
  return rp * 128 + ((((r & 1) << 6) | (gn << 4)) ^ ((rp & 7) << 4));
}

// ---- merged conversion: one launch does both G and X images (co-fills GPU)
__global__ void cvt_all_kernel(const float* __restrict__ U, const float* __restrict__ W,
                               const float* __restrict__ x,
                               char* __restrict__ Gt, char* __restrict__ Xt) {
  if (blockIdx.x < GCVT_BLKS) {
    int c = blockIdx.x * 256 + threadIdx.x;    // one 16B granule
    int g10 = c & 1023;
    int tile = c >> 10;                        // yblk*16 + ks
    int ks = tile & 15, yblk = tile >> 4;
    int r = g10 >> 2, gn = g10 & 3;
    int rg = yblk * 256 + r;
    int y = rg >> 1;
    uint4 o;
    if (y < NY) {
      const float* src = (rg & 1) ? W : U;
      const float4* p = (const float4*)(src + (size_t)y * ND + ks * BK + gn * 8);
      float4 f0 = p[0], f1 = p[1];
      o.x = pk2(f0.x, f0.y); o.y = pk2(f0.z, f0.w);
      o.z = pk2(f1.x, f1.y); o.w = pk2(f1.z, f1.w);
    } else {
      o = make_uint4(0u, 0u, 0u, 0u);
    }
    *(uint4*)(Gt + (size_t)tile * TILE + tile_off(r, gn)) = o;
  } else {
    int c = (blockIdx.x - GCVT_BLKS) * 256 + threadIdx.x;
    int g10 = c & 1023;
    int tile = c >> 10;                        // (b*10+t)*16 + ks
    int ks = tile & 15, rest = tile >> 4;
    int t = rest % NLT, b = rest / NLT;
    int r = g10 >> 2, gn = g10 & 3;
    int l = t * 256 + r;
    uint4 o;
    if (l < NL) {
      const float4* p = (const float4*)(x + ((size_t)b * NL + l) * ND + ks * BK + gn * 8);
      float4 f0 = p[0], f1 = p[1];
      o.x = pk2(f0.x, f0.y); o.y = pk2(f0.z, f0.w);
      o.z = pk2(f1.x, f1.y); o.w = pk2(f1.z, f1.w);
    } else {
      o = make_uint4(0u, 0u, 0u, 0u);
    }
    *(uint4*)(Xt + (size_t)tile * TILE + tile_off(r, gn)) = o;
  }
}

// ---- fused dual-GEMM + deferred softmax; 512 thr = 8 waves (2M x 4N), 256x256 tile
// m201 schedule, 6 barriers/K-tile: the trailing barriers of ph1/ph3 are removed
// (hazard-audited: the stage-writes they ordered target regions whose last readers
// are >=4 barriers upstream; lgkm ledgers are wave-local and unchanged).
// Publish points unchanged: VMC(2)+barrier at ph0 (odd half of THIS tile) and
// ph2 (even half of NEXT tile). Never drains mid-loop.
template<int LSPL, int NSPL, bool PARTIAL>
__global__ __launch_bounds__(512, 2) void fused_kernel(
    const char* __restrict__ Gt, const char* __restrict__ Xt,
    const float* __restrict__ bias, float* __restrict__ out,
    float* __restrict__ PD, float* __restrict__ PN)
{
  __shared__ uint4 ring[8192];         // 128 KB: A bufs [0,64K), B bufs [64K,128K)
  char* ringC = (char*)ring;

  constexpr int NKT = LSPL * 8;        // K-tiles (BK=64) per block

  const int tid  = threadIdx.x;
  const int lane = tid & 63;
  const int w    = tid >> 6;           // 0..7
  const int wr   = w >> 2;             // 0..1  M-half (128 G-rows)
  const int wc   = w & 3;              // 0..3  N-quarter (64 l)
  const int cl   = lane & 15, g = lane >> 4;

  const int id    = blockIdx.x;
  const int bb    = id & 7;            // batch, XCD-pinned
  const int n     = id >> 3;
  const int yblk  = n / NSPL;
  const int split = n - yblk * NSPL;
  const int tbase = split * LSPL;

  const char* GA = Gt + (size_t)yblk * NKS * TILE;
  const char* XB = Xt + ((size_t)bb * NLT + tbase) * NKS * TILE;

  f4v acc[8][4];
  float runD[8][2], runN[8][2];
  #pragma unroll
  for (int mi = 0; mi < 8; ++mi)
    #pragma unroll
    for (int p = 0; p < 2; ++p) { runD[mi][p] = 0.f; runN[mi][p] = 0.f; }

  int aoff[8], boff[4];
  #pragma unroll
  for (int j = 0; j < 8; ++j) aoff[j] = tile_off(wr * 128 + j * 16 + cl, g);
  #pragma unroll
  for (int ni = 0; ni < 4; ++ni) boff[ni] = tile_off(wc * 64 + ni * 16 + cl, g);

  const int t16 = tid << 4;
  auto stgA = [&](int kt1, int par) {  // 2 vm-events/wave: A slice -> buf kt1&1
    const char* ga = GA + (size_t)((((kt1 & 7) << 1) | par)) * TILE;
    char* la = ringC + (kt1 & 1) * 32768 + par * 16384 + (w << 10);
    async_copy16(ga + t16, la);
    async_copy16(ga + 8192 + t16, la + 8192);
  };
  auto stgB = [&](int kt1, int par) {
    const char* gb = XB + (size_t)((kt1 >> 3) * 16 + ((kt1 & 7) << 1) + par) * TILE;
    char* lb = ringC + 65536 + (kt1 & 1) * 32768 + par * 16384 + (w << 10);
    async_copy16(gb + t16, lb);
    async_copy16(gb + 8192 + t16, lb + 8192);
  };

  auto softmax_acc = [&](int tt) {     // deferred: per-lane sums, no shuffles
    const int lbase = (tbase + tt) * BN + wc * 64 + cl;
    #pragma unroll
    for (int mi = 0; mi < 8; ++mi) {
      #pragma unroll
      for (int p = 0; p < 2; ++p) {
        float se = 0.f, ste = 0.f;
        #pragma unroll
        for (int ni = 0; ni < 4; ++ni) {
          bool valid = (lbase + ni * 16) < NL;
          float sv = valid ? acc[mi][ni][2 * p] : -1e30f;
          float e = __expf(sv);
          se += e;
          ste += e * acc[mi][ni][2 * p + 1];
        }
        runD[mi][p] += se;
        runN[mi][p] += ste;
      }
    }
  };

#define SBAR __builtin_amdgcn_sched_barrier(0)
#define LGKM(N) asm volatile("s_waitcnt lgkmcnt(" #N ")" ::: "memory")
#define VMC(N)  asm volatile("s_waitcnt vmcnt(" #N ")" ::: "memory")

  // prologue: stage K-tile 0 fully (8 events); retire even half (vmcnt 4); publish
  stgA(0, 0); stgB(0, 0); stgA(0, 1); stgB(0, 1);
  VMC(4);
  __builtin_amdgcn_s_barrier();
  asm volatile("" ::: "memory");

  // frag registers (named sets, static indexing)
  s8v bvE[4], bvO[4], afX[4], afY[4];
  // primer: Q0 reads of kt=0 (even slice, buf 0)
  #pragma unroll
  for (int ni = 0; ni < 4; ++ni) bvE[ni] = *(const s8v*)(ringC + 65536 + boff[ni]);
  #pragma unroll
  for (int j = 0; j < 4; ++j)    afX[j] = *(const s8v*)(ringC + aoff[j]);

  for (int kt = 0; kt < NKT; ++kt) {
    const int buf = kt & 1;
    const char* Ae = ringC + buf * 32768;
    const char* Ao = Ae + 16384;
    const char* Bo = ringC + 65536 + buf * 32768 + 16384;
    const char* Aen = ringC + (buf ^ 1) * 32768;
    const char* Ben = ringC + 65536 + (buf ^ 1) * 32768;
    const bool hn = (kt + 1) < NKT;

    if ((kt & 7) == 0) {
      if (kt > 0) softmax_acc((kt >> 3) - 1);
      #pragma unroll
      for (int mi = 0; mi < 8; ++mi)
        #pragma unroll
        for (int ni = 0; ni < 4; ++ni)
          #pragma unroll
          for (int q = 0; q < 4; ++q) acc[mi][ni][q] = 0.f;
    }

    // ---- ph0: stage As0' | read afY(even hi) -> MFMA Q0 (afX,bvE) -> VMC -> bar
    if (hn) stgA(kt + 1, 0);
    #pragma unroll
    for (int j = 0; j < 4; ++j) afY[j] = *(const s8v*)(Ae + aoff[4 + j]);
    SBAR;
    __builtin_amdgcn_s_barrier();
    LGKM(4); SBAR;
    __builtin_amdgcn_s_setprio(1);
    #pragma unroll
    for (int j = 0; j < 4; ++j)
      #pragma unroll
      for (int ni = 0; ni < 4; ++ni)
        acc[j][ni] = __builtin_amdgcn_mfma_f32_16x16x32_bf16(afX[j], bvE[ni], acc[j][ni], 0, 0, 0);
    __builtin_amdgcn_s_setprio(0);
    if (hn) { VMC(2); } else { VMC(0); }   // publish odd half of THIS K-tile
    SBAR;
    __builtin_amdgcn_s_barrier();
    asm volatile("" ::: "memory");

    // ---- ph1: stage Bs0' | read bvO+afX(odd lo) -> MFMA Q1 (afY,bvE)
    if (hn) stgB(kt + 1, 0);
    #pragma unroll
    for (int ni = 0; ni < 4; ++ni) bvO[ni] = *(const s8v*)(Bo + boff[ni]);
    #pragma unroll
    for (int j = 0; j < 4; ++j)    afX[j] = *(const s8v*)(Ao + aoff[j]);
    SBAR;
    __builtin_amdgcn_s_barrier();
    LGKM(8); SBAR;
    __builtin_amdgcn_s_setprio(1);
    #pragma unroll
    for (int j = 0; j < 4; ++j)
      #pragma unroll
      for (int ni = 0; ni < 4; ++ni)
        acc[4 + j][ni] = __builtin_amdgcn_mfma_f32_16x16x32_bf16(afY[j], bvE[ni], acc[4 + j][ni], 0, 0, 0);
    __builtin_amdgcn_s_setprio(0);
    // (no trailing barrier: ph2's stage targets next-buf odd-A, readers >=4 bars away)

    // ---- ph2: stage As1' | read afY(odd hi) -> MFMA Q2 (afX,bvO) -> VMC -> bar
    if (hn) stgA(kt + 1, 1);
    #pragma unroll
    for (int j = 0; j < 4; ++j) afY[j] = *(const s8v*)(Ao + aoff[4 + j]);
    SBAR;
    __builtin_amdgcn_s_barrier();
    LGKM(4); SBAR;
    __builtin_amdgcn_s_setprio(1);
    #pragma unroll
    for (int j = 0; j < 4; ++j)
      #pragma unroll
      for (int ni = 0; ni < 4; ++ni)
        acc[j][ni] = __builtin_amdgcn_mfma_f32_16x16x32_bf16(afX[j], bvO[ni], acc[j][ni], 0, 0, 0);
    __builtin_amdgcn_s_setprio(0);
    if (hn) VMC(2);                        // publish even half of NEXT K-tile
    SBAR;
    __builtin_amdgcn_s_barrier();
    asm volatile("" ::: "memory");

    // ---- ph3: stage Bs1' | read bvE'+afX'(next even lo) -> MFMA Q3 (afY,bvO)
    if (hn) {
      stgB(kt + 1, 1);
      #pragma unroll
      for (int ni = 0; ni < 4; ++ni) bvE[ni] = *(const s8v*)(Ben + boff[ni]);
      #pragma unroll
      for (int j = 0; j < 4; ++j)    afX[j] = *(const s8v*)(Aen + aoff[j]);
      SBAR;
      __builtin_amdgcn_s_barrier();
      LGKM(8); SBAR;
    } else {
      SBAR;
      __builtin_amdgcn_s_barrier();
      LGKM(0); SBAR;
    }
    __builtin_amdgcn_s_setprio(1);
    #pragma unroll
    for (int j = 0; j < 4; ++j)
      #pragma unroll
      for (int ni = 0; ni < 4; ++ni)
        acc[4 + j][ni] = __builtin_amdgcn_mfma_f32_16x16x32_bf16(afY[j], bvO[ni], acc[4 + j][ni], 0, 0, 0);
    __builtin_amdgcn_s_setprio(0);
    // (no trailing barrier: next ph0's stage targets buf(kt) even-A, last read ph0-of-kt)
  }
  softmax_acc(LSPL - 1);

#undef SBAR
#undef LGKM
#undef VMC

  // ---- once-per-kernel: 16-lane reduce of partials (plain sums)
  #pragma unroll
  for (int mi = 0; mi < 8; ++mi)
    #pragma unroll
    for (int p = 0; p < 2; ++p) {
      float d = runD[mi][p], nn = runN[mi][p];
      #pragma unroll
      for (int off = 1; off < 16; off <<= 1) {
        d += __shfl_xor(d, off);
        nn += __shfl_xor(nn, off);
      }
      runD[mi][p] = d; runN[mi][p] = nn;
    }

  // ---- 4-way wc merge via LDS (plain sums), then write partials / output
  __syncthreads();
  float* sm = (float*)ring;      // 128 labels x 4 wc x 2 floats = 4 KB
  if (cl == 0) {
    #pragma unroll
    for (int mi = 0; mi < 8; ++mi)
      #pragma unroll
      for (int p = 0; p < 2; ++p) {
        int lab = wr * 64 + mi * 8 + 2 * g + p;   // 0..127
        float* s2 = sm + (lab * 4 + wc) * 2;
        s2[0] = runD[mi][p]; s2[1] = runN[mi][p];
      }
  }
  __syncthreads();
  if (tid < 128) {
    float D = 0.f, N = 0.f;
    #pragma unroll
    for (int q = 0; q < 4; ++q) {
      const float* s2 = sm + (tid * 4 + q) * 2;
      D += s2[0]; N += s2[1];
    }
    int y = yblk * 128 + tid;
    if constexpr (PARTIAL) {
      size_t o = ((size_t)split * NB + bb) * YPAD + y;
      PD[o] = D; PN[o] = N;
    } else {
      if (y < NY) out[(size_t)bb * NY + y] = N / D + bias[y];
    }
  }
}

// ---- merge SPLIT partials + bias -> out (plain sums)
__global__ void merge_kernel(const float* __restrict__ PD, const float* __restrict__ PN,
                             const float* __restrict__ bias, float* __restrict__ out) {
  int idx = blockIdx.x * 256 + threadIdx.x;      // NB*YPAD
  int b = idx / YPAD, y = idx - b * YPAD;
  if (y >= NY) return;
  float D = 0.f, N = 0.f;
  #pragma unroll
  for (int s = 0; s < SPLIT; ++s) {
    size_t o = ((size_t)s * NB + b) * YPAD + y;
    D += PD[o];
    N += PN[o];
  }
  out[(size_t)b * NY + y] = N / D + bias[y];
}

extern "C" void kernel_launch(void* const* d_in, const int* in_sizes, int n_in,
                              void* d_out, int out_size, void* d_ws, size_t ws_size,
                              hipStream_t stream) {
  const float* xf   = (const float*)d_in[0];
  const float* Uf   = (const float*)d_in[1];
  const float* Wf   = (const float*)d_in[2];
  const float* bias = (const float*)d_in[3];
  float* out = (float*)d_out;

  char* Gt = (char*)d_ws;
  char* Xt = Gt + GT_BYTES;
  float* PD = (float*)(Xt + XT_BYTES);
  float* PN = PD + P_ELEMS;

  // merged conversion: G blocks [0,4480) + X blocks [4480,9600), one launch
  cvt_all_kernel<<<GCVT_BLKS + XCVT_BLKS, 256, 0, stream>>>(Uf, Wf, xf, Gt, Xt);

  const size_t need_main = GT_BYTES + XT_BYTES + 2 * P_BYTES;   // ~42.2 MB
  if (ws_size >= need_main) {
    fused_kernel<LSPL_MAIN, SPLIT, true><<<NYB * NB * SPLIT, 512, 0, stream>>>(
        Gt, Xt, bias, out, PD, PN);
    merge_kernel<<<NB * YPAD / 256, 256, 0, stream>>>(PD, PN, bias, out);
  } else {
    fused_kernel<NLT, 1, false><<<NYB * NB, 512, 0, stream>>>(
        Gt, Xt, bias, out, PD, PN);
  }
}

// Round 21
// 345.052 us; speedup vs baseline: 1.2335x; 1.0275x over previous
//
#include <hip/hip_runtime.h>
#include <hip/hip_bf16.h>

// Problem constants
#define NB 8
#define NL 2500
#define ND 512
#define NY 8921

// Tiling
#define BM 256             // G rows per block (128 labels, U/W interleaved)
#define BN 256             // l-tile
#define BK 32              // k-slice (2 slices per K-tile of 64)
#define NKS 16             // slices per l-tile
#define LPAD 2560          // 10 * 256
#define NLT 10             // LPAD/BN
#define NYB 70             // ceil(NY/128)
#define YPAD 8960          // NYB*128

#define SPLIT 5            // l-range splits (2 l-tiles per block)
#define LSPL_MAIN 2

#define TILE 16384         // 256 rows x 32 bf16 (64B/row), row-pair swizzled image
#define GT_BYTES ((size_t)NYB * NKS * TILE)              // 18,350,080
#define XT_BYTES ((size_t)NB * NLT * NKS * TILE)         // 20,971,520
#define P_ELEMS  ((size_t)SPLIT * NB * YPAD)             // 358,400
#define P_BYTES  (P_ELEMS * 4)

#define GCVT_BLKS 4480     // G granules: 17920 rows * 64 / 256
#define XCVT_BLKS 5120     // X granules: 20480 rows * 64 / 256

typedef short s8v __attribute__((ext_vector_type(8)));
typedef float f4v __attribute__((ext_vector_type(4)));

__device__ __forceinline__ unsigned short f2bf(float f) {
  unsigned int u = __float_as_uint(f);
  return (unsigned short)((u + 0x7FFFu + ((u >> 16) & 1u)) >> 16);
}
__device__ __forceinline__ unsigned int pk2(float a, float b) {
  return (unsigned int)f2bf(a) | ((unsigned int)f2bf(b) << 16);
}
__device__ __forceinline__ void async_copy16(const char* g, char* l) {
  __builtin_amdgcn_global_load_lds(
      (const __attribute__((address_space(1))) void*)g,
      (__attribute__((address_space(3))) void*)l, 16, 0, 0);
}

// Swizzled tile byte offset for (row r in [0,256), 16B-granule gn in [0,4)):
// row-pair rp=r>>1 owns a 128B line; within-line = ((r&1)*64 + gn*16) ^ ((rp&7)<<4)
__device__ __forceinline__ int tile_off(int r, int gn) {
  int rp = r >> 1;
  return rp * 128 + ((((r & 1) << 6) | (gn << 4)) ^ ((rp & 7) << 4));
}

// ---- merged conversion: one launch does both G and X images (co-fills GPU)
__global__ void cvt_all_kernel(const float* __restrict__ U, const float* __restrict__ W,
                               const float* __restrict__ x,
                               char* __restrict__ Gt, char* __restrict__ Xt) {
  if (blockIdx.x < GCVT_BLKS) {
    int c = blockIdx.x * 256 + threadIdx.x;    // one 16B granule
    int g10 = c & 1023;
    int tile = c >> 10;                        // yblk*16 + ks
    int ks = tile & 15, yblk = tile >> 4;
    int r = g10 >> 2, gn = g10 & 3;
    int rg = yblk * 256 + r;
    int y = rg >> 1;
    uint4 o;
    if (y < NY) {
      const float* src = (rg & 1) ? W : U;
      const float4* p = (const float4*)(src + (size_t)y * ND + ks * BK + gn * 8);
      float4 f0 = p[0], f1 = p[1];
      o.x = pk2(f0.x, f0.y); o.y = pk2(f0.z, f0.w);
      o.z = pk2(f1.x, f1.y); o.w = pk2(f1.z, f1.w);
    } else {
      o = make_uint4(0u, 0u, 0u, 0u);
    }
    *(uint4*)(Gt + (size_t)tile * TILE + tile_off(r, gn)) = o;
  } else {
    int c = (blockIdx.x - GCVT_BLKS) * 256 + threadIdx.x;
    int g10 = c & 1023;
    int tile = c >> 10;                        // (b*10+t)*16 + ks
    int ks = tile & 15, rest = tile >> 4;
    int t = rest % NLT, b = rest / NLT;
    int r = g10 >> 2, gn = g10 & 3;
    int l = t * 256 + r;
    uint4 o;
    if (l < NL) {
      const float4* p = (const float4*)(x + ((size_t)b * NL + l) * ND + ks * BK + gn * 8);
      float4 f0 = p[0], f1 = p[1];
      o.x = pk2(f0.x, f0.y); o.y = pk2(f0.z, f0.w);
      o.z = pk2(f1.x, f1.y); o.w = pk2(f1.z, f1.w);
    } else {
      o = make_uint4(0u, 0u, 0u, 0u);
    }
    *(uint4*)(Xt + (size_t)tile * TILE + tile_off(r, gn)) = o;
  }
}

// ---- fused dual-GEMM + deferred softmax; 512 thr = 8 waves (2M x 4N), 256x256 tile
// m201 schedule, 4 barriers/K-tile: trailing barriers of ph1/ph3 removed (r20) AND
// pre-MFMA barriers of ph1/ph3 removed (this round) — both pacing-only: ph1 reads
// buf(kt) odd half, published at ph0's VMC(2)+barrier; ph3 reads buf(kt+1) even
// half, published at ph2's VMC(2)+barrier. lgkm ledgers wave-local, unchanged.
// Kept: ph0/ph2 pre-MFMA alignment barriers (bound wave drift to a half-tile) and
// the two VMC-publish barriers. Never drains mid-loop.
template<int LSPL, int NSPL, bool PARTIAL>
__global__ __launch_bounds__(512, 2) void fused_kernel(
    const char* __restrict__ Gt, const char* __restrict__ Xt,
    const float* __restrict__ bias, float* __restrict__ out,
    float* __restrict__ PD, float* __restrict__ PN)
{
  __shared__ uint4 ring[8192];         // 128 KB: A bufs [0,64K), B bufs [64K,128K)
  char* ringC = (char*)ring;

  constexpr int NKT = LSPL * 8;        // K-tiles (BK=64) per block

  const int tid  = threadIdx.x;
  const int lane = tid & 63;
  const int w    = tid >> 6;           // 0..7
  const int wr   = w >> 2;             // 0..1  M-half (128 G-rows)
  const int wc   = w & 3;              // 0..3  N-quarter (64 l)
  const int cl   = lane & 15, g = lane >> 4;

  const int id    = blockIdx.x;
  const int bb    = id & 7;            // batch, XCD-pinned
  const int n     = id >> 3;
  const int yblk  = n / NSPL;
  const int split = n - yblk * NSPL;
  const int tbase = split * LSPL;

  const char* GA = Gt + (size_t)yblk * NKS * TILE;
  const char* XB = Xt + ((size_t)bb * NLT + tbase) * NKS * TILE;

  f4v acc[8][4];
  float runD[8][2], runN[8][2];
  #pragma unroll
  for (int mi = 0; mi < 8; ++mi)
    #pragma unroll
    for (int p = 0; p < 2; ++p) { runD[mi][p] = 0.f; runN[mi][p] = 0.f; }

  int aoff[8], boff[4];
  #pragma unroll
  for (int j = 0; j < 8; ++j) aoff[j] = tile_off(wr * 128 + j * 16 + cl, g);
  #pragma unroll
  for (int ni = 0; ni < 4; ++ni) boff[ni] = tile_off(wc * 64 + ni * 16 + cl, g);

  const int t16 = tid << 4;
  auto stgA = [&](int kt1, int par) {  // 2 vm-events/wave: A slice -> buf kt1&1
    const char* ga = GA + (size_t)((((kt1 & 7) << 1) | par)) * TILE;
    char* la = ringC + (kt1 & 1) * 32768 + par * 16384 + (w << 10);
    async_copy16(ga + t16, la);
    async_copy16(ga + 8192 + t16, la + 8192);
  };
  auto stgB = [&](int kt1, int par) {
    const char* gb = XB + (size_t)((kt1 >> 3) * 16 + ((kt1 & 7) << 1) + par) * TILE;
    char* lb = ringC + 65536 + (kt1 & 1) * 32768 + par * 16384 + (w << 10);
    async_copy16(gb + t16, lb);
    async_copy16(gb + 8192 + t16, lb + 8192);
  };

  auto softmax_acc = [&](int tt) {     // deferred: per-lane sums, no shuffles
    const int lbase = (tbase + tt) * BN + wc * 64 + cl;
    #pragma unroll
    for (int mi = 0; mi < 8; ++mi) {
      #pragma unroll
      for (int p = 0; p < 2; ++p) {
        float se = 0.f, ste = 0.f;
        #pragma unroll
        for (int ni = 0; ni < 4; ++ni) {
          bool valid = (lbase + ni * 16) < NL;
          float sv = valid ? acc[mi][ni][2 * p] : -1e30f;
          float e = __expf(sv);
          se += e;
          ste += e * acc[mi][ni][2 * p + 1];
        }
        runD[mi][p] += se;
        runN[mi][p] += ste;
      }
    }
  };

#define SBAR __builtin_amdgcn_sched_barrier(0)
#define LGKM(N) asm volatile("s_waitcnt lgkmcnt(" #N ")" ::: "memory")
#define VMC(N)  asm volatile("s_waitcnt vmcnt(" #N ")" ::: "memory")

  // prologue: stage K-tile 0 fully (8 events); retire even half (vmcnt 4); publish
  stgA(0, 0); stgB(0, 0); stgA(0, 1); stgB(0, 1);
  VMC(4);
  __builtin_amdgcn_s_barrier();
  asm volatile("" ::: "memory");

  // frag registers (named sets, static indexing)
  s8v bvE[4], bvO[4], afX[4], afY[4];
  // primer: Q0 reads of kt=0 (even slice, buf 0)
  #pragma unroll
  for (int ni = 0; ni < 4; ++ni) bvE[ni] = *(const s8v*)(ringC + 65536 + boff[ni]);
  #pragma unroll
  for (int j = 0; j < 4; ++j)    afX[j] = *(const s8v*)(ringC + aoff[j]);

  for (int kt = 0; kt < NKT; ++kt) {
    const int buf = kt & 1;
    const char* Ae = ringC + buf * 32768;
    const char* Ao = Ae + 16384;
    const char* Bo = ringC + 65536 + buf * 32768 + 16384;
    const char* Aen = ringC + (buf ^ 1) * 32768;
    const char* Ben = ringC + 65536 + (buf ^ 1) * 32768;
    const bool hn = (kt + 1) < NKT;

    if ((kt & 7) == 0) {
      if (kt > 0) softmax_acc((kt >> 3) - 1);
      #pragma unroll
      for (int mi = 0; mi < 8; ++mi)
        #pragma unroll
        for (int ni = 0; ni < 4; ++ni)
          #pragma unroll
          for (int q = 0; q < 4; ++q) acc[mi][ni][q] = 0.f;
    }

    // ---- ph0: stage As0' | read afY(even hi) -> bar -> MFMA Q0 (afX,bvE) -> VMC -> bar
    if (hn) stgA(kt + 1, 0);
    #pragma unroll
    for (int j = 0; j < 4; ++j) afY[j] = *(const s8v*)(Ae + aoff[4 + j]);
    SBAR;
    __builtin_amdgcn_s_barrier();
    LGKM(4); SBAR;
    __builtin_amdgcn_s_setprio(1);
    #pragma unroll
    for (int j = 0; j < 4; ++j)
      #pragma unroll
      for (int ni = 0; ni < 4; ++ni)
        acc[j][ni] = __builtin_amdgcn_mfma_f32_16x16x32_bf16(afX[j], bvE[ni], acc[j][ni], 0, 0, 0);
    __builtin_amdgcn_s_setprio(0);
    if (hn) { VMC(2); } else { VMC(0); }   // publish odd half of THIS K-tile
    SBAR;
    __builtin_amdgcn_s_barrier();
    asm volatile("" ::: "memory");

    // ---- ph1: stage Bs0' | read bvO+afX(odd lo) -> MFMA Q1 (afY,bvE)  [no barriers]
    if (hn) stgB(kt + 1, 0);
    #pragma unroll
    for (int ni = 0; ni < 4; ++ni) bvO[ni] = *(const s8v*)(Bo + boff[ni]);
    #pragma unroll
    for (int j = 0; j < 4; ++j)    afX[j] = *(const s8v*)(Ao + aoff[j]);
    SBAR;
    LGKM(8); SBAR;
    __builtin_amdgcn_s_setprio(1);
    #pragma unroll
    for (int j = 0; j < 4; ++j)
      #pragma unroll
      for (int ni = 0; ni < 4; ++ni)
        acc[4 + j][ni] = __builtin_amdgcn_mfma_f32_16x16x32_bf16(afY[j], bvE[ni], acc[4 + j][ni], 0, 0, 0);
    __builtin_amdgcn_s_setprio(0);

    // ---- ph2: stage As1' | read afY(odd hi) -> bar -> MFMA Q2 (afX,bvO) -> VMC -> bar
    if (hn) stgA(kt + 1, 1);
    #pragma unroll
    for (int j = 0; j < 4; ++j) afY[j] = *(const s8v*)(Ao + aoff[4 + j]);
    SBAR;
    __builtin_amdgcn_s_barrier();
    LGKM(4); SBAR;
    __builtin_amdgcn_s_setprio(1);
    #pragma unroll
    for (int j = 0; j < 4; ++j)
      #pragma unroll
      for (int ni = 0; ni < 4; ++ni)
        acc[j][ni] = __builtin_amdgcn_mfma_f32_16x16x32_bf16(afX[j], bvO[ni], acc[j][ni], 0, 0, 0);
    __builtin_amdgcn_s_setprio(0);
    if (hn) VMC(2);                        // publish even half of NEXT K-tile
    SBAR;
    __builtin_amdgcn_s_barrier();
    asm volatile("" ::: "memory");

    // ---- ph3: stage Bs1' | read bvE'+afX'(next even lo) -> MFMA Q3 (afY,bvO)  [no barriers]
    if (hn) {
      stgB(kt + 1, 1);
      #pragma unroll
      for (int ni = 0; ni < 4; ++ni) bvE[ni] = *(const s8v*)(Ben + boff[ni]);
      #pragma unroll
      for (int j = 0; j < 4; ++j)    afX[j] = *(const s8v*)(Aen + aoff[j]);
      SBAR;
      LGKM(8); SBAR;
    } else {
      SBAR;
      LGKM(0); SBAR;
    }
    __builtin_amdgcn_s_setprio(1);
    #pragma unroll
    for (int j = 0; j < 4; ++j)
      #pragma unroll
      for (int ni = 0; ni < 4; ++ni)
        acc[4 + j][ni] = __builtin_amdgcn_mfma_f32_16x16x32_bf16(afY[j], bvO[ni], acc[4 + j][ni], 0, 0, 0);
    __builtin_amdgcn_s_setprio(0);
  }
  softmax_acc(LSPL - 1);

#undef SBAR
#undef LGKM
#undef VMC

  // ---- once-per-kernel: 16-lane reduce of partials (plain sums)
  #pragma unroll
  for (int mi = 0; mi < 8; ++mi)
    #pragma unroll
    for (int p = 0; p < 2; ++p) {
      float d = runD[mi][p], nn = runN[mi][p];
      #pragma unroll
      for (int off = 1; off < 16; off <<= 1) {
        d += __shfl_xor(d, off);
        nn += __shfl_xor(nn, off);
      }
      runD[mi][p] = d; runN[mi][p] = nn;
    }

  // ---- 4-way wc merge via LDS (plain sums), then write partials / output
  __syncthreads();
  float* sm = (float*)ring;      // 128 labels x 4 wc x 2 floats = 4 KB
  if (cl == 0) {
    #pragma unroll
    for (int mi = 0; mi < 8; ++mi)
      #pragma unroll
      for (int p = 0; p < 2; ++p) {
        int lab = wr * 64 + mi * 8 + 2 * g + p;   // 0..127
        float* s2 = sm + (lab * 4 + wc) * 2;
        s2[0] = runD[mi][p]; s2[1] = runN[mi][p];
      }
  }
  __syncthreads();
  if (tid < 128) {
    float D = 0.f, N = 0.f;
    #pragma unroll
    for (int q = 0; q < 4; ++q) {
      const float* s2 = sm + (tid * 4 + q) * 2;
      D += s2[0]; N += s2[1];
    }
    int y = yblk * 128 + tid;
    if constexpr (PARTIAL) {
      size_t o = ((size_t)split * NB + bb) * YPAD + y;
      PD[o] = D; PN[o] = N;
    } else {
      if (y < NY) out[(size_t)bb * NY + y] = N / D + bias[y];
    }
  }
}

// ---- merge SPLIT partials + bias -> out (plain sums)
__global__ void merge_kernel(const float* __restrict__ PD, const float* __restrict__ PN,
                             const float* __restrict__ bias, float* __restrict__ out) {
  int idx = blockIdx.x * 256 + threadIdx.x;      // NB*YPAD
  int b = idx / YPAD, y = idx - b * YPAD;
  if (y >= NY) return;
  float D = 0.f, N = 0.f;
  #pragma unroll
  for (int s = 0; s < SPLIT; ++s) {
    size_t o = ((size_t)s * NB + b) * YPAD + y;
    D += PD[o];
    N += PN[o];
  }
  out[(size_t)b * NY + y] = N / D + bias[y];
}

extern "C" void kernel_launch(void* const* d_in, const int* in_sizes, int n_in,
                              void* d_out, int out_size, void* d_ws, size_t ws_size,
                              hipStream_t stream) {
  const float* xf   = (const float*)d_in[0];
  const float* Uf   = (const float*)d_in[1];
  const float* Wf   = (const float*)d_in[2];
  const float* bias = (const float*)d_in[3];
  float* out = (float*)d_out;

  char* Gt = (char*)d_ws;
  char* Xt = Gt + GT_BYTES;
  float* PD = (float*)(Xt + XT_BYTES);
  float* PN = PD + P_ELEMS;

  // merged conversion: G blocks [0,4480) + X blocks [4480,9600), one launch
  cvt_all_kernel<<<GCVT_BLKS + XCVT_BLKS, 256, 0, stream>>>(Uf, Wf, xf, Gt, Xt);

  const size_t need_main = GT_BYTES + XT_BYTES + 2 * P_BYTES;   // ~42.2 MB
  if (ws_size >= need_main) {
    fused_kernel<LSPL_MAIN, SPLIT, true><<<NYB * NB * SPLIT, 512, 0, stream>>>(
        Gt, Xt, bias, out, PD, PN);
    merge_kernel<<<NB * YPAD / 256, 256, 0, stream>>>(PD, PN, bias, out);
  } else {
    fused_kernel<NLT, 1, false><<<NYB * NB, 512, 0, stream>>>(
        Gt, Xt, bias, out, PD, PN);
  }
}